// Round 1
// baseline (141.128 us; speedup 1.0000x reference)
//
#include <hip/hip_runtime.h>

// OpenBoundary neighbor list, N=8192, cutoff=5.0, max_neighbours=32.
// Outputs (int32, concatenated): to_idx[8192][32] | cell_indices[8192][32][3]=0 | actual_max (scalar)

constexpr int   N      = 8192;
constexpr int   MAXNB  = 32;
constexpr float CUT2   = 25.0f;   // 5.0^2, exactly representable
constexpr int   ROWS_PER_WAVE = 4;

__global__ __launch_bounds__(256) void neigh_kernel(const float* __restrict__ pos,
                                                    int* __restrict__ out_idx,
                                                    int* __restrict__ out_max) {
    const int gwave = (blockIdx.x * blockDim.x + threadIdx.x) >> 6;
    const int lane  = threadIdx.x & 63;
    const int row0  = gwave * ROWS_PER_WAVE;

    // Row (query) positions — wave-uniform values.
    float xi[ROWS_PER_WAVE], yi[ROWS_PER_WAVE], zi[ROWS_PER_WAVE];
#pragma unroll
    for (int r = 0; r < ROWS_PER_WAVE; ++r) {
        const int i = row0 + r;
        xi[r] = pos[3 * i + 0];
        yi[r] = pos[3 * i + 1];
        zi[r] = pos[3 * i + 2];
    }

    int count[ROWS_PER_WAVE];
#pragma unroll
    for (int r = 0; r < ROWS_PER_WAVE; ++r) count[r] = 0;

    for (int b = 0; b < N; b += 64) {
        const int j = b + lane;
        const float xj = pos[3 * j + 0];
        const float yj = pos[3 * j + 1];
        const float zj = pos[3 * j + 2];
#pragma unroll
        for (int r = 0; r < ROWS_PER_WAVE; ++r) {
            const int i = row0 + r;
            // Match numpy f32 rounding exactly: no FMA contraction, ((dx^2+dy^2)+dz^2)
            const float dx = __fsub_rn(xi[r], xj);
            const float dy = __fsub_rn(yi[r], yj);
            const float dz = __fsub_rn(zi[r], zj);
            const float r2 = __fadd_rn(__fadd_rn(__fmul_rn(dx, dx), __fmul_rn(dy, dy)),
                                       __fmul_rn(dz, dz));
            const bool hit = (r2 <= CUT2) && (j != i);
            const unsigned long long m = __ballot(hit);
            if (hit) {
                // prefix popcount of m below this lane -> ascending-j compaction slot
                const int pre = __builtin_amdgcn_mbcnt_hi(
                    (unsigned int)(m >> 32),
                    __builtin_amdgcn_mbcnt_lo((unsigned int)m, 0u));
                const int p = count[r] + pre;
                if (p < MAXNB) out_idx[i * MAXNB + p] = j;
            }
            count[r] += __popcll(m);
        }
    }

    // Fill unused slots with -1 (disjoint from hit-written slots).
#pragma unroll
    for (int r = 0; r < ROWS_PER_WAVE; ++r) {
        if (lane >= count[r] && lane < MAXNB) out_idx[(row0 + r) * MAXNB + lane] = -1;
    }

    // Scalar: max over rows of the FULL neighbor count (not clamped to 32).
    int mx = count[0];
#pragma unroll
    for (int r = 1; r < ROWS_PER_WAVE; ++r) mx = max(mx, count[r]);
    if (lane == 0) atomicMax(out_max, mx);
}

extern "C" void kernel_launch(void* const* d_in, const int* in_sizes, int n_in,
                              void* d_out, int out_size, void* d_ws, size_t ws_size,
                              hipStream_t stream) {
    const float* pos = (const float*)d_in[0];   // [8192, 3] f32
    // d_in[1] = max_neighbours scalar (always 32) — compile-time constant here.

    int* out      = (int*)d_out;
    int* out_idx  = out;                              // [8192*32]
    int* zero_beg = out + N * MAXNB;                  // cell_indices + max slot
    int* out_max  = out + N * MAXNB + N * MAXNB * 3;  // scalar

    // Zero cell_indices (8192*32*3) and the max slot (atomicMax accumulates on top).
    hipMemsetAsync(zero_beg, 0, (size_t)(N * MAXNB * 3 + 1) * sizeof(int), stream);

    const int waves  = N / ROWS_PER_WAVE;   // 2048
    const int block  = 256;                 // 4 waves/block
    const int grid   = waves * 64 / block;  // 512 blocks
    neigh_kernel<<<grid, block, 0, stream>>>(pos, out_idx, out_max);
}

// Round 2
// 120.361 us; speedup vs baseline: 1.1725x; 1.1725x over previous
//
#include <hip/hip_runtime.h>

// OpenBoundary neighbor list, N=8192, cutoff=5.0, max_neighbours=32.
// Outputs (int32, concatenated): to_idx[8192][32] | cell_indices[8192][32][3]=0 | actual_max (scalar)
//
// R2 structure: LDS-staged positions (2 passes x 48KB), ballot-compaction,
// 4 rows/wave, 512-thread blocks, 256 blocks (1/CU).

constexpr int   N     = 8192;
constexpr int   MAXNB = 32;
constexpr float CUT2  = 25.0f;   // 5.0^2 exactly representable
constexpr int   R     = 4;       // rows per wave
constexpr int   HALF  = 4096;    // j-points staged per pass
constexpr int   BLOCK = 512;     // 8 waves -> 32 rows per block

__global__ __launch_bounds__(BLOCK) void neigh_kernel(const float* __restrict__ pos,
                                                      int* __restrict__ out) {
    __shared__ float s[3 * HALF];          // 48 KB, interleaved xyz

    const int lane = threadIdx.x & 63;
    const int wave = threadIdx.x >> 6;     // 0..7
    const int row0 = blockIdx.x * (BLOCK / 64) * R + wave * R;

    int* __restrict__ out_idx = out;                               // [N*MAXNB]
    int* __restrict__ cell    = out + N * MAXNB;                   // [N*MAXNB*3] -> zeros
    int* __restrict__ out_max = out + N * MAXNB + N * MAXNB * 3;   // scalar

    // Zero this block's slice of cell_indices (32 rows x 96 ints = 12 KB), coalesced.
    {
        int* c = cell + blockIdx.x * (BLOCK / 64) * R * MAXNB * 3;
        #pragma unroll
        for (int t = threadIdx.x; t < (BLOCK / 64) * R * MAXNB * 3; t += BLOCK) c[t] = 0;
    }

    // Query-row positions (wave-uniform), straight from global (L2-resident).
    float xi[R], yi[R], zi[R];
    #pragma unroll
    for (int r = 0; r < R; ++r) {
        const int i = row0 + r;
        xi[r] = pos[3 * i + 0];
        yi[r] = pos[3 * i + 1];
        zi[r] = pos[3 * i + 2];
    }

    int count[R];
    #pragma unroll
    for (int r = 0; r < R; ++r) count[r] = 0;

    const float4* p4 = (const float4*)pos;   // 6144 float4 total
    float4* s4 = (float4*)s;                 // 3072 float4 per pass

    for (int pass = 0; pass < 2; ++pass) {
        if (pass) __syncthreads();           // waves done reading previous LDS contents
        // Stage 48 KB: 3072 float4 / 512 threads = 6 per thread, fully coalesced.
        #pragma unroll
        for (int t = threadIdx.x; t < 3 * HALF / 4; t += BLOCK)
            s4[t] = p4[pass * (3 * HALF / 4) + t];
        __syncthreads();

        const int jbase = pass * HALF;

        // Register double-buffer of this lane's j-point.
        int a0 = 3 * lane;
        float xc = s[a0], yc = s[a0 + 1], zc = s[a0 + 2];

        for (int b = 0; b < HALF; b += 64) {
            // Prefetch next chunk (address clamped on last iter; value unused).
            const int an = 3 * ((b + 64 < HALF ? b + 64 : 0) + lane);
            const float xn = s[an], yn = s[an + 1], zn = s[an + 2];

            const int j = jbase + b + lane;
            #pragma unroll
            for (int r = 0; r < R; ++r) {
                const int i = row0 + r;
                // numpy f32 rounding: no FMA contraction, ((dx^2+dy^2)+dz^2)
                const float dx = __fsub_rn(xi[r], xc);
                const float dy = __fsub_rn(yi[r], yc);
                const float dz = __fsub_rn(zi[r], zc);
                const float r2 = __fadd_rn(__fadd_rn(__fmul_rn(dx, dx), __fmul_rn(dy, dy)),
                                           __fmul_rn(dz, dz));
                const bool hit = (r2 <= CUT2) && (j != i);
                const unsigned long long m = __ballot(hit);
                if (hit) {
                    const int pre = __builtin_amdgcn_mbcnt_hi(
                        (unsigned int)(m >> 32),
                        __builtin_amdgcn_mbcnt_lo((unsigned int)m, 0u));
                    const int p = count[r] + pre;
                    if (p < MAXNB) out_idx[i * MAXNB + p] = j;
                }
                count[r] += __popcll(m);
            }
            xc = xn; yc = yn; zc = zn;
        }
    }

    // Fill unused slots with -1 (disjoint from hit-written slots).
    #pragma unroll
    for (int r = 0; r < R; ++r) {
        if (lane >= count[r] && lane < MAXNB) out_idx[(row0 + r) * MAXNB + lane] = -1;
    }

    // Scalar: max over rows of the FULL neighbor count (not clamped to 32).
    int mx = count[0];
    #pragma unroll
    for (int r = 1; r < R; ++r) mx = max(mx, count[r]);
    if (lane == 0) atomicMax(out_max, mx);
}

extern "C" void kernel_launch(void* const* d_in, const int* in_sizes, int n_in,
                              void* d_out, int out_size, void* d_ws, size_t ws_size,
                              hipStream_t stream) {
    const float* pos = (const float*)d_in[0];   // [8192, 3] f32
    int* out = (int*)d_out;

    // Zero only the 4-byte scalar slot (atomicMax accumulates on top).
    hipMemsetAsync(out + N * MAXNB + N * MAXNB * 3, 0, sizeof(int), stream);

    const int rows_per_block = (BLOCK / 64) * R;          // 32
    const int grid = N / rows_per_block;                  // 256 blocks = 1/CU
    neigh_kernel<<<grid, BLOCK, 0, stream>>>(pos, out);
}